// Round 1
// baseline (234.261 us; speedup 1.0000x reference)
//
#include <hip/hip_runtime.h>

typedef unsigned short u16;
typedef __bf16 bf16x8 __attribute__((ext_vector_type(8)));
typedef float f32x4 __attribute__((ext_vector_type(4)));

__device__ __forceinline__ u16 f32_to_bf16(float f) {
  union { float f; unsigned u; } v; v.f = f;
  unsigned r = v.u + 0x7FFFu + ((v.u >> 16) & 1u);
  return (u16)(r >> 16);
}

// ---------------------------------------------------------------------------
// Transpose + fp32->bf16 convert:  src[K][N] f32  ->  dst[N][K] bf16
// ---------------------------------------------------------------------------
__global__ __launch_bounds__(256) void transpose_cvt(
    const float* __restrict__ src, u16* __restrict__ dst, int K, int N) {
  __shared__ float tile[64][65];
  int k0 = blockIdx.y * 64, n0 = blockIdx.x * 64;
  int t = threadIdx.x;
  int c = t & 63, r4 = t >> 6;
#pragma unroll
  for (int rr = r4; rr < 64; rr += 4)
    tile[rr][c] = src[(size_t)(k0 + rr) * N + n0 + c];
  __syncthreads();
#pragma unroll
  for (int rr = r4; rr < 64; rr += 4)
    dst[(size_t)(n0 + rr) * K + k0 + c] = f32_to_bf16(tile[c][rr]);
}

// ---------------------------------------------------------------------------
// LayerNorm: x[4096][1024] f32 -> xn bf16
// ---------------------------------------------------------------------------
__global__ __launch_bounds__(256) void ln_kernel(
    const float* __restrict__ x, const float* __restrict__ gamma,
    const float* __restrict__ beta, u16* __restrict__ xn) {
  int row = blockIdx.x;
  int t = threadIdx.x;
  const float4 v = ((const float4*)(x + (size_t)row * 1024))[t];
  float s = v.x + v.y + v.z + v.w;
  float ss = v.x * v.x + v.y * v.y + v.z * v.z + v.w * v.w;
#pragma unroll
  for (int m = 1; m < 64; m <<= 1) {
    s += __shfl_xor(s, m, 64);
    ss += __shfl_xor(ss, m, 64);
  }
  __shared__ float as_[4], ass[4];
  int wave = t >> 6;
  if ((t & 63) == 0) { as_[wave] = s; ass[wave] = ss; }
  __syncthreads();
  s = as_[0] + as_[1] + as_[2] + as_[3];
  ss = ass[0] + ass[1] + ass[2] + ass[3];
  float mu = s * (1.0f / 1024.0f);
  float var = ss * (1.0f / 1024.0f) - mu * mu;
  float rstd = rsqrtf(var + 1e-5f);
  float4 g = ((const float4*)gamma)[t];
  float4 b = ((const float4*)beta)[t];
  uint2 o;
  o.x = (unsigned)f32_to_bf16((v.x - mu) * rstd * g.x + b.x) |
        ((unsigned)f32_to_bf16((v.y - mu) * rstd * g.y + b.y) << 16);
  o.y = (unsigned)f32_to_bf16((v.z - mu) * rstd * g.z + b.z) |
        ((unsigned)f32_to_bf16((v.w - mu) * rstd * g.w + b.w) << 16);
  ((uint2*)(xn + (size_t)row * 1024))[t] = o;
}

// ---------------------------------------------------------------------------
// bf16 GEMM: C[M][N] = A[M][K] @ Bt[N][K]^T   (Bt is pre-transposed, bf16)
// BM=BN=128, BK=64, 256 threads (4 waves, 2x2), each wave 64x64 via 4x4 MFMA
// OUT_MODE 0: bf16 store;  1: f32 store + bias
// ---------------------------------------------------------------------------
template <int OUT_MODE>
__global__ __launch_bounds__(256) void gemm_bf16_k(
    const u16* __restrict__ A, const u16* __restrict__ Bt,
    void* __restrict__ Cv, const float* __restrict__ bias,
    int M, int N, int K, int ldc) {
  __shared__ __align__(16) u16 sA[128 * 72];  // [128][64] padded to 72
  __shared__ __align__(16) u16 sB[128 * 72];
  int t = threadIdx.x;
  int m0 = blockIdx.y * 128, n0 = blockIdx.x * 128;
  int wave = t >> 6, lane = t & 63;
  int wm = wave >> 1, wn = wave & 1;
  int l15 = lane & 15, quad = lane >> 4;

  f32x4 acc[4][4];
#pragma unroll
  for (int i = 0; i < 4; i++)
#pragma unroll
    for (int j = 0; j < 4; j++) acc[i][j] = f32x4{0.f, 0.f, 0.f, 0.f};

  int r = t >> 3, q = t & 7;  // staging: rows r,r+32,r+64,r+96 ; 16B chunk q
  const u16* Ap = A + (size_t)(m0 + r) * K + q * 8;
  const u16* Bp = Bt + (size_t)(n0 + r) * K + q * 8;

  for (int k0 = 0; k0 < K; k0 += 64) {
    uint4 av0 = *(const uint4*)(Ap + k0);
    uint4 av1 = *(const uint4*)(Ap + k0 + (size_t)32 * K);
    uint4 av2 = *(const uint4*)(Ap + k0 + (size_t)64 * K);
    uint4 av3 = *(const uint4*)(Ap + k0 + (size_t)96 * K);
    uint4 bv0 = *(const uint4*)(Bp + k0);
    uint4 bv1 = *(const uint4*)(Bp + k0 + (size_t)32 * K);
    uint4 bv2 = *(const uint4*)(Bp + k0 + (size_t)64 * K);
    uint4 bv3 = *(const uint4*)(Bp + k0 + (size_t)96 * K);
    __syncthreads();  // previous iteration's reads complete
    *(uint4*)&sA[(r) * 72 + q * 8] = av0;
    *(uint4*)&sA[(r + 32) * 72 + q * 8] = av1;
    *(uint4*)&sA[(r + 64) * 72 + q * 8] = av2;
    *(uint4*)&sA[(r + 96) * 72 + q * 8] = av3;
    *(uint4*)&sB[(r) * 72 + q * 8] = bv0;
    *(uint4*)&sB[(r + 32) * 72 + q * 8] = bv1;
    *(uint4*)&sB[(r + 64) * 72 + q * 8] = bv2;
    *(uint4*)&sB[(r + 96) * 72 + q * 8] = bv3;
    __syncthreads();
#pragma unroll
    for (int ks = 0; ks < 2; ++ks) {
      bf16x8 af[4], bf[4];
#pragma unroll
      for (int mi = 0; mi < 4; mi++)
        af[mi] = *(const bf16x8*)&sA[(wm * 64 + mi * 16 + l15) * 72 + ks * 32 + quad * 8];
#pragma unroll
      for (int ni = 0; ni < 4; ni++)
        bf[ni] = *(const bf16x8*)&sB[(wn * 64 + ni * 16 + l15) * 72 + ks * 32 + quad * 8];
#pragma unroll
      for (int mi = 0; mi < 4; mi++)
#pragma unroll
        for (int ni = 0; ni < 4; ni++)
          acc[mi][ni] = __builtin_amdgcn_mfma_f32_16x16x32_bf16(
              af[mi], bf[ni], acc[mi][ni], 0, 0, 0);
    }
  }
#pragma unroll
  for (int mi = 0; mi < 4; mi++)
#pragma unroll
    for (int ni = 0; ni < 4; ni++) {
      int row = m0 + wm * 64 + mi * 16 + quad * 4;
      int col = n0 + wn * 64 + ni * 16 + l15;
#pragma unroll
      for (int rr = 0; rr < 4; rr++) {
        float vv = acc[mi][ni][rr];
        if (OUT_MODE == 0)
          ((u16*)Cv)[(size_t)(row + rr) * ldc + col] = f32_to_bf16(vv);
        else
          ((float*)Cv)[(size_t)(row + rr) * ldc + col] = vv + bias[col];
      }
    }
}

// ---------------------------------------------------------------------------
// Flash-style GQA attention (non-causal, unnormalized-exp online softmax).
// qkv[4096][1536] bf16 (q | k | v). Block = (q-tile of 64, b*16+h).
// 4 waves; wave owns 16 query rows. Key tiles of 64.
// ---------------------------------------------------------------------------
__global__ __launch_bounds__(256) void attn_kernel(
    const u16* __restrict__ qkv, u16* __restrict__ attn_out) {
  const int LD = 1536;
  int qt = blockIdx.x;       // 0..31
  int bh = blockIdx.y;       // 0..31
  int b = bh >> 4, h = bh & 15, g = h >> 2;

  __shared__ __align__(16) u16 sK[64 * 72];      // [key][d]
  __shared__ __align__(16) u16 sV[64 * 72];      // [d][key]  (transposed)
  __shared__ __align__(16) u16 sP[4 * 16 * 72];  // per-wave [16 q][64 key]

  int t = threadIdx.x, wave = t >> 6, lane = t & 63;
  int l15 = lane & 15, quad = lane >> 4;

  const u16* qbase = qkv + (size_t)(b * 2048 + qt * 64) * LD + h * 64;
  const u16* kbase = qkv + (size_t)(b * 2048) * LD + 1024 + g * 64;
  const u16* vbase = kbase + 256;

  // Q A-fragments (held in registers): rows wave*16 .. +15
  bf16x8 qf[2];
#pragma unroll
  for (int ks = 0; ks < 2; ++ks)
    qf[ks] = *(const bf16x8*)(qbase + (size_t)(wave * 16 + l15) * LD + ks * 32 + quad * 8);

  f32x4 oacc[4];
#pragma unroll
  for (int i = 0; i < 4; i++) oacc[i] = f32x4{0.f, 0.f, 0.f, 0.f};
  float lsum[4] = {0.f, 0.f, 0.f, 0.f};

  const float cexp = 0.125f * 1.44269504088896f;  // SCALE * log2(e)
  int sr = t >> 3, sq = t & 7;  // K staging coords

  for (int kt = 0; kt < 32; ++kt) {
    __syncthreads();  // previous tile's LDS reads complete
    // stage K tile [64 key][64 d]
#pragma unroll
    for (int i = 0; i < 2; ++i) {
      int rr = sr + 32 * i;
      *(uint4*)&sK[rr * 72 + sq * 8] =
          *(const uint4*)(kbase + (size_t)(kt * 64 + rr) * LD + sq * 8);
    }
    // stage V tile transposed -> sV[d][key]
    {
      int kv = t & 63, db = (t >> 6) * 16;
      const u16* vp = vbase + (size_t)(kt * 64 + kv) * LD + db;
      uint4 v0 = *(const uint4*)vp;
      uint4 v1 = *(const uint4*)(vp + 8);
      u16 tmp[16];
      *(uint4*)tmp = v0;
      *(uint4*)(tmp + 8) = v1;
#pragma unroll
      for (int j = 0; j < 16; ++j) sV[(db + j) * 72 + kv] = tmp[j];
    }
    __syncthreads();

    // S = Q K^T  (wave's 16 rows x 64 keys)
    f32x4 sacc[4];
#pragma unroll
    for (int i = 0; i < 4; i++) sacc[i] = f32x4{0.f, 0.f, 0.f, 0.f};
#pragma unroll
    for (int ni = 0; ni < 4; ++ni)
#pragma unroll
      for (int ks = 0; ks < 2; ++ks) {
        bf16x8 kf = *(const bf16x8*)&sK[(ni * 16 + l15) * 72 + ks * 32 + quad * 8];
        sacc[ni] = __builtin_amdgcn_mfma_f32_16x16x32_bf16(qf[ks], kf, sacc[ni], 0, 0, 0);
      }

    // p = exp(S*scale)  (no max subtraction; logits bounded ~5)
    u16* sPw = sP + wave * 16 * 72;
#pragma unroll
    for (int ni = 0; ni < 4; ++ni) {
#pragma unroll
      for (int rr = 0; rr < 4; ++rr) {
        float p = exp2f(sacc[ni][rr] * cexp);
        lsum[rr] += p;
        sPw[(quad * 4 + rr) * 72 + ni * 16 + l15] = f32_to_bf16(p);
      }
    }
    // PV: O += P V   (P read back in A-layout from wave-private LDS; DS ops
    // are in-order per wave, region is wave-exclusive -> no barrier needed)
#pragma unroll
    for (int ks = 0; ks < 2; ++ks) {
      bf16x8 pf = *(const bf16x8*)&sPw[l15 * 72 + ks * 32 + quad * 8];
#pragma unroll
      for (int ni = 0; ni < 4; ++ni) {
        bf16x8 vf = *(const bf16x8*)&sV[(ni * 16 + l15) * 72 + ks * 32 + quad * 8];
        oacc[ni] = __builtin_amdgcn_mfma_f32_16x16x32_bf16(pf, vf, oacc[ni], 0, 0, 0);
      }
    }
  }

  // row sums across the 16 lanes holding each row, then normalize + store
#pragma unroll
  for (int rr = 0; rr < 4; ++rr) {
#pragma unroll
    for (int m = 1; m < 16; m <<= 1) lsum[rr] += __shfl_xor(lsum[rr], m, 64);
    lsum[rr] = 1.0f / lsum[rr];
  }
  u16* obase = attn_out + (size_t)(b * 2048 + qt * 64 + wave * 16) * 1024 + h * 64;
#pragma unroll
  for (int ni = 0; ni < 4; ++ni)
#pragma unroll
    for (int rr = 0; rr < 4; ++rr)
      obase[(size_t)(quad * 4 + rr) * 1024 + ni * 16 + l15] =
          f32_to_bf16(oacc[ni][rr] * lsum[rr]);
}

// ---------------------------------------------------------------------------
extern "C" void kernel_launch(void* const* d_in, const int* in_sizes, int n_in,
                              void* d_out, int out_size, void* d_ws, size_t ws_size,
                              hipStream_t stream) {
  const float* x = (const float*)d_in[0];
  const float* gamma = (const float*)d_in[1];
  const float* beta = (const float*)d_in[2];
  const float* w_q = (const float*)d_in[3];
  const float* w_k = (const float*)d_in[4];
  const float* w_v = (const float*)d_in[5];
  const float* w_o = (const float*)d_in[6];
  const float* b_o = (const float*)d_in[7];
  float* out = (float*)d_out;

  char* ws = (char*)d_ws;
  u16* wqkvT = (u16*)ws;                              // [1536][1024] bf16, 3 MB
  u16* woT = (u16*)(ws + 3u * 1024 * 1024);           // [1024][1024] bf16, 2 MB
  u16* xn = (u16*)(ws + 5u * 1024 * 1024);            // [4096][1024] bf16, 8 MB
  u16* qkv = (u16*)(ws + 13u * 1024 * 1024);          // [4096][1536] bf16, 12 MB
  u16* attn = (u16*)(ws + 25u * 1024 * 1024);         // [4096][1024] bf16, 8 MB

  transpose_cvt<<<dim3(16, 16), 256, 0, stream>>>(w_q, wqkvT, 1024, 1024);
  transpose_cvt<<<dim3(4, 16), 256, 0, stream>>>(w_k, wqkvT + 1024 * 1024, 1024, 256);
  transpose_cvt<<<dim3(4, 16), 256, 0, stream>>>(w_v, wqkvT + 1280 * 1024, 1024, 256);
  transpose_cvt<<<dim3(16, 16), 256, 0, stream>>>(w_o, woT, 1024, 1024);

  ln_kernel<<<4096, 256, 0, stream>>>(x, gamma, beta, xn);

  // qkv = xn @ [w_q | w_k | w_v]
  gemm_bf16_k<0><<<dim3(12, 32), 256, 0, stream>>>(xn, wqkvT, qkv, nullptr,
                                                   4096, 1536, 1024, 1536);

  attn_kernel<<<dim3(32, 32), 256, 0, stream>>>(qkv, attn);

  // out = attn @ w_o + b_o
  gemm_bf16_k<1><<<dim3(8, 32), 256, 0, stream>>>(attn, woT, out, b_o,
                                                  4096, 1024, 1024, 1024);
}

// Round 2
// 201.185 us; speedup vs baseline: 1.1644x; 1.1644x over previous
//
#include <hip/hip_runtime.h>

typedef unsigned short u16;
typedef __bf16 bf16x8 __attribute__((ext_vector_type(8)));
typedef short s16x4 __attribute__((ext_vector_type(4)));
typedef float f32x4 __attribute__((ext_vector_type(4)));

__device__ __forceinline__ u16 f32_to_bf16(float f) {
  union { float f; unsigned u; } v; v.f = f;
  unsigned r = v.u + 0x7FFFu + ((v.u >> 16) & 1u);
  return (u16)(r >> 16);
}
__device__ __forceinline__ unsigned f2u(float f) { union { float f; unsigned u; } v; v.f = f; return v.u; }
__device__ __forceinline__ float u2f(unsigned u) { union { unsigned u; float f; } v; v.u = u; return v.f; }

// ---------------------------------------------------------------------------
// Merged transpose + fp32->bf16 convert for all 4 weights (1 dispatch).
// src[K=1024][N] f32 -> dst[N][1024] bf16
// ---------------------------------------------------------------------------
__global__ __launch_bounds__(256) void transpose_cvt_multi(
    const float* __restrict__ w_q, const float* __restrict__ w_k,
    const float* __restrict__ w_v, const float* __restrict__ w_o,
    u16* __restrict__ wqkvT, u16* __restrict__ woT) {
  const float* src; u16* dst; int N;
  switch (blockIdx.z) {
    case 0: src = w_q; dst = wqkvT; N = 1024; break;
    case 1: src = w_k; dst = wqkvT + 1024 * 1024; N = 256; break;
    case 2: src = w_v; dst = wqkvT + 1280 * 1024; N = 256; break;
    default: src = w_o; dst = woT; N = 1024; break;
  }
  int n0 = blockIdx.x * 64;
  if (n0 >= N) return;
  const int K = 1024;
  __shared__ float tile[64][65];
  int k0 = blockIdx.y * 64;
  int t = threadIdx.x;
  int c = t & 63, r4 = t >> 6;
#pragma unroll
  for (int rr = r4; rr < 64; rr += 4)
    tile[rr][c] = src[(size_t)(k0 + rr) * N + n0 + c];
  __syncthreads();
#pragma unroll
  for (int rr = r4; rr < 64; rr += 4)
    dst[(size_t)(n0 + rr) * K + k0 + c] = f32_to_bf16(tile[c][rr]);
}

// ---------------------------------------------------------------------------
// LayerNorm: x[4096][1024] f32 -> xn bf16
// ---------------------------------------------------------------------------
__global__ __launch_bounds__(256) void ln_kernel(
    const float* __restrict__ x, const float* __restrict__ gamma,
    const float* __restrict__ beta, u16* __restrict__ xn) {
  int row = blockIdx.x;
  int t = threadIdx.x;
  const float4 v = ((const float4*)(x + (size_t)row * 1024))[t];
  float s = v.x + v.y + v.z + v.w;
  float ss = v.x * v.x + v.y * v.y + v.z * v.z + v.w * v.w;
#pragma unroll
  for (int m = 1; m < 64; m <<= 1) {
    s += __shfl_xor(s, m, 64);
    ss += __shfl_xor(ss, m, 64);
  }
  __shared__ float as_[4], ass[4];
  int wave = t >> 6;
  if ((t & 63) == 0) { as_[wave] = s; ass[wave] = ss; }
  __syncthreads();
  s = as_[0] + as_[1] + as_[2] + as_[3];
  ss = ass[0] + ass[1] + ass[2] + ass[3];
  float mu = s * (1.0f / 1024.0f);
  float var = ss * (1.0f / 1024.0f) - mu * mu;
  float rstd = rsqrtf(var + 1e-5f);
  float4 g = ((const float4*)gamma)[t];
  float4 b = ((const float4*)beta)[t];
  uint2 o;
  o.x = (unsigned)f32_to_bf16((v.x - mu) * rstd * g.x + b.x) |
        ((unsigned)f32_to_bf16((v.y - mu) * rstd * g.y + b.y) << 16);
  o.y = (unsigned)f32_to_bf16((v.z - mu) * rstd * g.z + b.z) |
        ((unsigned)f32_to_bf16((v.w - mu) * rstd * g.w + b.w) << 16);
  ((uint2*)(xn + (size_t)row * 1024))[t] = o;
}

// ---------------------------------------------------------------------------
// bf16 GEMM: C[M][N] = A[M][K] @ Bt[N][K]^T   (Bt pre-transposed, bf16)
// BM=BN=128, BK=64, 256 threads (4 waves 2x2), wave 64x64 via 4x4 MFMA
// ---------------------------------------------------------------------------
template <int OUT_MODE>
__global__ __launch_bounds__(256) void gemm_bf16_k(
    const u16* __restrict__ A, const u16* __restrict__ Bt,
    void* __restrict__ Cv, const float* __restrict__ bias,
    int M, int N, int K, int ldc) {
  __shared__ __align__(16) u16 sA[128 * 72];
  __shared__ __align__(16) u16 sB[128 * 72];
  int t = threadIdx.x;
  int m0 = blockIdx.y * 128, n0 = blockIdx.x * 128;
  int wave = t >> 6, lane = t & 63;
  int wm = wave >> 1, wn = wave & 1;
  int l15 = lane & 15, quad = lane >> 4;

  f32x4 acc[4][4];
#pragma unroll
  for (int i = 0; i < 4; i++)
#pragma unroll
    for (int j = 0; j < 4; j++) acc[i][j] = f32x4{0.f, 0.f, 0.f, 0.f};

  int r = t >> 3, q = t & 7;
  const u16* Ap = A + (size_t)(m0 + r) * K + q * 8;
  const u16* Bp = Bt + (size_t)(n0 + r) * K + q * 8;

  for (int k0 = 0; k0 < K; k0 += 64) {
    uint4 av0 = *(const uint4*)(Ap + k0);
    uint4 av1 = *(const uint4*)(Ap + k0 + (size_t)32 * K);
    uint4 av2 = *(const uint4*)(Ap + k0 + (size_t)64 * K);
    uint4 av3 = *(const uint4*)(Ap + k0 + (size_t)96 * K);
    uint4 bv0 = *(const uint4*)(Bp + k0);
    uint4 bv1 = *(const uint4*)(Bp + k0 + (size_t)32 * K);
    uint4 bv2 = *(const uint4*)(Bp + k0 + (size_t)64 * K);
    uint4 bv3 = *(const uint4*)(Bp + k0 + (size_t)96 * K);
    __syncthreads();
    *(uint4*)&sA[(r) * 72 + q * 8] = av0;
    *(uint4*)&sA[(r + 32) * 72 + q * 8] = av1;
    *(uint4*)&sA[(r + 64) * 72 + q * 8] = av2;
    *(uint4*)&sA[(r + 96) * 72 + q * 8] = av3;
    *(uint4*)&sB[(r) * 72 + q * 8] = bv0;
    *(uint4*)&sB[(r + 32) * 72 + q * 8] = bv1;
    *(uint4*)&sB[(r + 64) * 72 + q * 8] = bv2;
    *(uint4*)&sB[(r + 96) * 72 + q * 8] = bv3;
    __syncthreads();
#pragma unroll
    for (int ks = 0; ks < 2; ++ks) {
      bf16x8 af[4], bf[4];
#pragma unroll
      for (int mi = 0; mi < 4; mi++)
        af[mi] = *(const bf16x8*)&sA[(wm * 64 + mi * 16 + l15) * 72 + ks * 32 + quad * 8];
#pragma unroll
      for (int ni = 0; ni < 4; ni++)
        bf[ni] = *(const bf16x8*)&sB[(wn * 64 + ni * 16 + l15) * 72 + ks * 32 + quad * 8];
#pragma unroll
      for (int mi = 0; mi < 4; mi++)
#pragma unroll
        for (int ni = 0; ni < 4; ni++)
          acc[mi][ni] = __builtin_amdgcn_mfma_f32_16x16x32_bf16(
              af[mi], bf[ni], acc[mi][ni], 0, 0, 0);
    }
  }
#pragma unroll
  for (int mi = 0; mi < 4; mi++)
#pragma unroll
    for (int ni = 0; ni < 4; ni++) {
      int row = m0 + wm * 64 + mi * 16 + quad * 4;
      int col = n0 + wn * 64 + ni * 16 + l15;
#pragma unroll
      for (int rr = 0; rr < 4; rr++) {
        float vv = acc[mi][ni][rr];
        if (OUT_MODE == 0)
          ((u16*)Cv)[(size_t)(row + rr) * ldc + col] = f32_to_bf16(vv);
        else
          ((float*)Cv)[(size_t)(row + rr) * ldc + col] = vv + bias[col];
      }
    }
}

// ---------------------------------------------------------------------------
// Flash-style GQA attention v2: S^T = K Q^T, P stays in registers,
// PV via mfma_f32_16x16x16bf16_1k computing O^T = V^T P^T.
// Block = (q-tile 64, b*16+h), 4 waves x 16 q. K/V prefetched into regs.
// ---------------------------------------------------------------------------
__global__ __launch_bounds__(256) void attn_kernel(
    const u16* __restrict__ qkv, u16* __restrict__ attn_out) {
  const int LD = 1536;
  int qt = blockIdx.x;   // 0..31
  int bh = blockIdx.y;   // 0..31
  int b = bh >> 4, h = bh & 15, g = h >> 2;

  __shared__ __align__(16) u16 sK[64 * 72];  // [key][d]
  __shared__ __align__(16) u16 sV[64 * 72];  // [d][key] (transposed, packed)

  int t = threadIdx.x, wave = t >> 6, lane = t & 63;
  int l15 = lane & 15, quad = lane >> 4;

  const u16* qbase = qkv + (size_t)(b * 2048 + qt * 64) * LD + h * 64;
  const u16* kbase = qkv + (size_t)(b * 2048) * LD + 1024 + g * 64;
  const u16* vbase = kbase + 256;

  // Q fragments (B-operand of S^T MFMA): rows wave*16 .. +15
  bf16x8 qf[2];
#pragma unroll
  for (int ks = 0; ks < 2; ++ks)
    qf[ks] = *(const bf16x8*)(qbase + (size_t)(wave * 16 + l15) * LD + ks * 32 + quad * 8);

  f32x4 oacc[4];
#pragma unroll
  for (int i = 0; i < 4; i++) oacc[i] = f32x4{0.f, 0.f, 0.f, 0.f};
  float lsum = 0.f;

  const float cexp = 0.125f * 1.44269504088896f;  // SCALE * log2(e)
  int sr = t >> 3, sq = t & 7;           // K staging: rows sr, sr+32; chunk sq
  int vkp = (t & 31) * 2, vdc = (t >> 5) * 8;  // V staging: key pair, d-chunk

  // prologue: prefetch tile 0 into registers
  uint4 ka0, ka1, va0, va1;
  {
    const u16* kp0 = kbase + (size_t)sr * LD + sq * 8;
    ka0 = *(const uint4*)kp0;
    ka1 = *(const uint4*)(kp0 + (size_t)32 * LD);
    const u16* vp0 = vbase + (size_t)vkp * LD + vdc;
    va0 = *(const uint4*)vp0;
    va1 = *(const uint4*)(vp0 + LD);
  }

  for (int kt = 0; kt < 32; ++kt) {
    __syncthreads();  // all waves done reading previous tile's LDS
    // stage K [key][d]
    *(uint4*)&sK[sr * 72 + sq * 8] = ka0;
    *(uint4*)&sK[(sr + 32) * 72 + sq * 8] = ka1;
    // stage V transposed [d][key], packed u32 writes (2 keys per word)
    {
      const unsigned* aw = (const unsigned*)&va0;
      const unsigned* bw = (const unsigned*)&va1;
#pragma unroll
      for (int w = 0; w < 4; ++w) {
        unsigned lo = (aw[w] & 0xFFFFu) | (bw[w] << 16);
        unsigned hi = (aw[w] >> 16) | (bw[w] & 0xFFFF0000u);
        *(unsigned*)&sV[(vdc + 2 * w) * 72 + vkp] = lo;
        *(unsigned*)&sV[(vdc + 2 * w + 1) * 72 + vkp] = hi;
      }
    }
    __syncthreads();

    // prefetch next tile while computing this one
    if (kt < 31) {
      const u16* kp0 = kbase + (size_t)((kt + 1) * 64 + sr) * LD + sq * 8;
      ka0 = *(const uint4*)kp0;
      ka1 = *(const uint4*)(kp0 + (size_t)32 * LD);
      const u16* vp0 = vbase + (size_t)((kt + 1) * 64 + vkp) * LD + vdc;
      va0 = *(const uint4*)vp0;
      va1 = *(const uint4*)(vp0 + LD);
    }

    // S^T = K Q^T : D[m=key][n=q], lane holds keys ni*16+quad*4+rr, q=l15
    f32x4 sacc[4];
#pragma unroll
    for (int i = 0; i < 4; i++) sacc[i] = f32x4{0.f, 0.f, 0.f, 0.f};
#pragma unroll
    for (int ni = 0; ni < 4; ++ni)
#pragma unroll
      for (int ks = 0; ks < 2; ++ks) {
        bf16x8 kf = *(const bf16x8*)&sK[(ni * 16 + l15) * 72 + ks * 32 + quad * 8];
        sacc[ni] = __builtin_amdgcn_mfma_f32_16x16x32_bf16(kf, qf[ks], sacc[ni], 0, 0, 0);
      }

    // softmax numerator; pack P^T directly into 16x16x16 B-fragments
    s16x4 pf[4];
#pragma unroll
    for (int ni = 0; ni < 4; ++ni) {
      unsigned r0, r1, r2, r3;
      {
        float p = __builtin_amdgcn_exp2f(sacc[ni][0] * cexp);
        r0 = (f2u(p) + 0x8000u) & 0xFFFF0000u; lsum += u2f(r0);
        p = __builtin_amdgcn_exp2f(sacc[ni][1] * cexp);
        r1 = (f2u(p) + 0x8000u) & 0xFFFF0000u; lsum += u2f(r1);
        p = __builtin_amdgcn_exp2f(sacc[ni][2] * cexp);
        r2 = (f2u(p) + 0x8000u) & 0xFFFF0000u; lsum += u2f(r2);
        p = __builtin_amdgcn_exp2f(sacc[ni][3] * cexp);
        r3 = (f2u(p) + 0x8000u) & 0xFFFF0000u; lsum += u2f(r3);
      }
      uint2 pk;
      pk.x = (r0 >> 16) | r1;
      pk.y = (r2 >> 16) | r3;
      pf[ni] = *(s16x4*)&pk;
    }

    // O^T += V^T P^T : A-frag = V^T[d=md*16+l15][key=ni*16+quad*4+j]
#pragma unroll
    for (int md = 0; md < 4; ++md)
#pragma unroll
      for (int ni = 0; ni < 4; ++ni) {
        s16x4 vf = *(const s16x4*)&sV[(md * 16 + l15) * 72 + ni * 16 + quad * 4];
        oacc[md] = __builtin_amdgcn_mfma_f32_16x16x16bf16_1k(vf, pf[ni], oacc[md], 0, 0, 0);
      }
  }

  // lane holds O^T[d][q=l15] partial-free; lsum partial over this quad's keys:
  // reduce across quads (lanes l15, l15+16, l15+32, l15+48)
  lsum += __shfl_xor(lsum, 16, 64);
  lsum += __shfl_xor(lsum, 32, 64);
  float rinv = 1.0f / lsum;

  u16* obase = attn_out + (size_t)(b * 2048 + qt * 64 + wave * 16 + l15) * 1024 +
               h * 64 + quad * 4;
#pragma unroll
  for (int md = 0; md < 4; ++md) {
    unsigned r0 = (f2u(oacc[md][0] * rinv) + 0x8000u) & 0xFFFF0000u;
    unsigned r1 = (f2u(oacc[md][1] * rinv) + 0x8000u) & 0xFFFF0000u;
    unsigned r2 = (f2u(oacc[md][2] * rinv) + 0x8000u) & 0xFFFF0000u;
    unsigned r3 = (f2u(oacc[md][3] * rinv) + 0x8000u) & 0xFFFF0000u;
    uint2 o;
    o.x = (r0 >> 16) | r1;
    o.y = (r2 >> 16) | r3;
    *(uint2*)(obase + md * 16) = o;
  }
}

// ---------------------------------------------------------------------------
extern "C" void kernel_launch(void* const* d_in, const int* in_sizes, int n_in,
                              void* d_out, int out_size, void* d_ws, size_t ws_size,
                              hipStream_t stream) {
  const float* x = (const float*)d_in[0];
  const float* gamma = (const float*)d_in[1];
  const float* beta = (const float*)d_in[2];
  const float* w_q = (const float*)d_in[3];
  const float* w_k = (const float*)d_in[4];
  const float* w_v = (const float*)d_in[5];
  const float* w_o = (const float*)d_in[6];
  const float* b_o = (const float*)d_in[7];
  float* out = (float*)d_out;

  char* ws = (char*)d_ws;
  u16* wqkvT = (u16*)ws;                       // [1536][1024] bf16, 3 MB
  u16* woT = (u16*)(ws + 3u * 1024 * 1024);    // [1024][1024] bf16, 2 MB
  u16* xn = (u16*)(ws + 5u * 1024 * 1024);     // [4096][1024] bf16, 8 MB
  u16* qkv = (u16*)(ws + 13u * 1024 * 1024);   // [4096][1536] bf16, 12 MB
  u16* attn = (u16*)(ws + 25u * 1024 * 1024);  // [4096][1024] bf16, 8 MB

  transpose_cvt_multi<<<dim3(16, 16, 4), 256, 0, stream>>>(w_q, w_k, w_v, w_o,
                                                           wqkvT, woT);
  ln_kernel<<<4096, 256, 0, stream>>>(x, gamma, beta, xn);

  gemm_bf16_k<0><<<dim3(12, 32), 256, 0, stream>>>(xn, wqkvT, qkv, nullptr,
                                                   4096, 1536, 1024, 1536);

  attn_kernel<<<dim3(32, 32), 256, 0, stream>>>(qkv, attn);

  gemm_bf16_k<1><<<dim3(8, 32), 256, 0, stream>>>(attn, woT, out, b_o,
                                                  4096, 1024, 1024, 1024);
}